// Round 7
// baseline (538.854 us; speedup 1.0000x reference)
//
#include <hip/hip_runtime.h>

// Trilinear gridding, owner-computes (zero global atomics):
//   B=32, N=65536, scale=128 -> s=64, G=128, out = 32 x 128^3 f32 (256 MB).
// Pipeline: counting-sort points by (batch, 8x8x32-cell tile); one 256-thread
// block OWNS each 8x8x32 vertex tile; wave w of 4 scans neighbor (ex,ey) pair
// w's sorted range; accumulate in LDS; write tile with exclusive coalesced
// 128B-line stores. No grid zeroing needed.
// Round-6 lesson: 64-thread gather blocks serialized 4 index-load+scan
// chains with ~50% lane idle -> this version parallelizes them across waves.

#define BLK 256
// tile geometry (vertices / cells per bin): 8 x 8 x 32
#define RX 8
#define RY 8
#define RZ 32
#define TILE_N (RX * RY * RZ)            // 2048 floats = 8 KB LDS
#define NBINS 32768                      // out_size / 2048 (std shape)
#define SCAN_CHUNK 256
#define NCHUNK (NBINS / SCAN_CHUNK)      // 128

// d_ws byte layout
#define HIST_OFF    0
#define PREFIX_OFF  ((size_t)NBINS * 4)
#define CURSOR_OFF  ((size_t)NBINS * 8)   // after scatter, cursor[bin] == end
#define PART_OFF    ((size_t)NBINS * 12)
#define PARTEXC_OFF ((size_t)NBINS * 12 + (size_t)NCHUNK * 4)
#define SORTED_OFF  ((size_t)2 * 1024 * 1024)

__global__ void zero_kernel(float4* __restrict__ out, int n4) {
    int i = blockIdx.x * blockDim.x + threadIdx.x;
    const int stride = gridDim.x * blockDim.x;
    for (; i < n4; i += stride) out[i] = float4{0.f, 0.f, 0.f, 0.f};
}

__device__ __forceinline__ bool point_geom(const float* pts, const int* scale_p,
                                           int i, int total_pts, int out_size,
                                           float& x, float& y, float& z,
                                           int& bin, int& b) {
    const int scale = scale_p[0];
    const int s = scale >> 1;
    const int G = 2 * s;
    const int CX = G / RX, CY = G / RY, CZ = G / RZ;
    const int B = out_size / (G * G * G);
    const int N = total_pts / B;
    const float fs = (float)s;
    x = pts[3 * i + 0] * fs;
    y = pts[3 * i + 1] * fs;
    z = pts[3 * i + 2] * fs;
    if (x + y + z == 0.0f) return false;  // reference mask
    const int cx = (int)floorf(x) + s;    // lower-corner vertex index
    const int cy = (int)floorf(y) + s;
    const int cz = (int)floorf(z) + s;
    b = i / N;
    bin = ((b * CX + (cx / RX)) * CY + (cy / RY)) * CZ + (cz / RZ);
    return true;
}

__global__ void hist_kernel(const float* __restrict__ pts, const int* __restrict__ scale_p,
                            int* __restrict__ hist, int total_pts, int out_size) {
    int i = blockIdx.x * blockDim.x + threadIdx.x;
    if (i >= total_pts) return;
    float x, y, z; int bin, b;
    if (!point_geom(pts, scale_p, i, total_pts, out_size, x, y, z, bin, b)) return;
    atomicAdd(hist + bin, 1);
}

__global__ void scan_partial(const int* __restrict__ hist, int* __restrict__ partial) {
    __shared__ int red[BLK / 64];
    int i = blockIdx.x * BLK + threadIdx.x;
    int v = hist[i];
    for (int o = 32; o > 0; o >>= 1) v += __shfl_down(v, o);
    if ((threadIdx.x & 63) == 0) red[threadIdx.x >> 6] = v;
    __syncthreads();
    if (threadIdx.x == 0) {
        int t = 0;
        for (int w = 0; w < BLK / 64; ++w) t += red[w];
        partial[blockIdx.x] = t;
    }
}

__global__ void scan_top(const int* __restrict__ partial, int* __restrict__ partExc) {
    __shared__ int sm[NCHUNK];
    const int t = threadIdx.x;            // blockDim.x == NCHUNK
    sm[t] = partial[t];
    __syncthreads();
    for (int o = 1; o < NCHUNK; o <<= 1) {
        int v = (t >= o) ? sm[t - o] : 0;
        __syncthreads();
        sm[t] += v;
        __syncthreads();
    }
    partExc[t] = (t == 0) ? 0 : sm[t - 1];
}

__global__ void scan_chunks(const int* __restrict__ hist, const int* __restrict__ partExc,
                            int* __restrict__ prefix, int* __restrict__ cursor) {
    __shared__ int sm[SCAN_CHUNK];
    const int t = threadIdx.x;
    const int base = blockIdx.x * SCAN_CHUNK;
    sm[t] = hist[base + t];
    __syncthreads();
    for (int o = 1; o < SCAN_CHUNK; o <<= 1) {
        int v = (t >= o) ? sm[t - o] : 0;
        __syncthreads();
        sm[t] += v;
        __syncthreads();
    }
    const int exc = ((t == 0) ? 0 : sm[t - 1]) + partExc[blockIdx.x];
    prefix[base + t] = exc;
    cursor[base + t] = exc;
}

__global__ void scatter_kernel(const float* __restrict__ pts, const int* __restrict__ scale_p,
                               int* __restrict__ cursor, float4* __restrict__ sorted,
                               int total_pts, int out_size) {
    int i = blockIdx.x * blockDim.x + threadIdx.x;
    if (i >= total_pts) return;
    float x, y, z; int bin, b;
    if (!point_geom(pts, scale_p, i, total_pts, out_size, x, y, z, bin, b)) return;
    const int pos = atomicAdd(cursor + bin, 1);
    sorted[pos] = make_float4(x, y, z, (float)b);   // pre-scaled coords
}

// One 256-thread block per (batch, 8x8x32 vertex tile). Wave w (of 4) scans
// neighbor-bin pair (ex,ey) = (w&1, w>>1); accumulate in LDS; store tile.
__global__ void __launch_bounds__(256) gather_kernel(
        const float4* __restrict__ sorted, const int* __restrict__ prefix,
        const int* __restrict__ binEnd, const int* __restrict__ scale_p,
        float* __restrict__ out, int out_size) {
    const int scale = scale_p[0];
    const int s = scale >> 1;
    const int G = 2 * s;
    const int CX = G / RX, CY = G / RY, CZ = G / RZ;

    int id = blockIdx.x;
    const int bz = id % CZ; id /= CZ;
    const int by = id % CY; id /= CY;
    const int bx = id % CX;
    const int b  = id / CX;

    const int X0 = bx * RX, Y0 = by * RY, Z0 = bz * RZ;
    const int w = threadIdx.x >> 6;       // wave id 0..3
    const int lane = threadIdx.x & 63;

    __shared__ float tile[TILE_N];        // 8 KB
#pragma unroll
    for (int k = 0; k < TILE_N / 256; ++k)
        tile[threadIdx.x + 256 * k] = 0.0f;
    __syncthreads();

    const int xb = bx - 1 + (w & 1);      // <= bx < CX, only lower bound check
    const int yb = by - 1 + (w >> 1);
    if (xb >= 0 && yb >= 0) {
        const int zlo = (bz > 0) ? bz - 1 : 0;
        const int rowBase = ((b * CX + xb) * CY + yb) * CZ;
        const int start = prefix[rowBase + zlo];
        const int end   = binEnd[rowBase + bz];
        for (int j = start + lane; j < end; j += 64) {
            const float4 q = sorted[j];
            const float flx = floorf(q.x), fly = floorf(q.y), flz = floorf(q.z);
            const int ix = (int)flx + s;
            const int iy = (int)fly + s;
            const int iz = (int)flz + s;
            // corners ix..ix+1 must intersect [X0, X0+RX) etc.
            if (ix < X0 - 1 || ix > X0 + RX - 1 ||
                iy < Y0 - 1 || iy > Y0 + RY - 1 ||
                iz < Z0 - 1 || iz > Z0 + RZ - 1) continue;
            const float ax = q.x - flx, ay = q.y - fly, az = q.z - flz;
            const float wx[2] = {1.0f - ax, ax};
            const float wy[2] = {1.0f - ay, ay};
            const float wz[2] = {1.0f - az, az};
#pragma unroll
            for (int dx = 0; dx < 2; ++dx) {
                const int vx = ix + dx - X0;
                if ((unsigned)vx >= RX) continue;
#pragma unroll
                for (int dy = 0; dy < 2; ++dy) {
                    const int vy = iy + dy - Y0;
                    if ((unsigned)vy >= RY) continue;
#pragma unroll
                    for (int dz = 0; dz < 2; ++dz) {
                        const int vz = iz + dz - Z0;
                        if ((unsigned)vz >= RZ) continue;
                        atomicAdd(&tile[(vx * RY + vy) * RZ + vz],
                                  wx[dx] * wy[dy] * wz[dz]);
                    }
                }
            }
        }
    }
    __syncthreads();

    // store: thread t writes 8 consecutive z-floats (2x float4); each 128B
    // output line (one (x,y) row's z-block of 32) is owned by this block only.
    const int l = threadIdx.x * 8;
    const int vx = l >> 8, vy = (l >> 5) & 7, vz0 = l & 31;
    float* dst = out + (size_t)b * (size_t)(G * G * G)
                     + ((size_t)(X0 + vx) * G + (Y0 + vy)) * G + Z0 + vz0;
    const float4* src = (const float4*)&tile[l];
    ((float4*)dst)[0] = src[0];
    ((float4*)dst)[1] = src[1];
}

// Fallback: naive one-thread-per-point scatter (needs zeroed out).
__global__ void naive_kernel(const float* __restrict__ pts, const int* __restrict__ scale_p,
                             float* __restrict__ out, int total_pts, int out_size) {
    int i = blockIdx.x * blockDim.x + threadIdx.x;
    if (i >= total_pts) return;
    float x, y, z; int bin, b;
    if (!point_geom(pts, scale_p, i, total_pts, out_size, x, y, z, bin, b)) return;
    const int scale = scale_p[0];
    const int s = scale >> 1;
    const int G = 2 * s;
    const float flx = floorf(x), fly = floorf(y), flz = floorf(z);
    const float ax = x - flx, ay = y - fly, az = z - flz;
    const int ix = (int)flx + s, iy = (int)fly + s, iz = (int)flz + s;
    const float wx[2] = {1.0f - ax, ax};
    const float wy[2] = {1.0f - ay, ay};
    const float wz[2] = {1.0f - az, az};
    float* g = out + (size_t)b * (size_t)(G * G * G);
    const int base = (ix * G + iy) * G + iz;
#pragma unroll
    for (int dx = 0; dx < 2; ++dx)
#pragma unroll
        for (int dy = 0; dy < 2; ++dy)
#pragma unroll
            for (int dz = 0; dz < 2; ++dz)
                atomicAdd(&g[base + (dx * G + dy) * G + dz], wx[dx] * wy[dy] * wz[dz]);
}

extern "C" void kernel_launch(void* const* d_in, const int* in_sizes, int n_in,
                              void* d_out, int out_size, void* d_ws, size_t ws_size,
                              hipStream_t stream) {
    const float* pts = (const float*)d_in[0];
    const int* scale_p = (const int*)d_in[1];
    float* out = (float*)d_out;
    char* ws = (char*)d_ws;

    const int total_pts = in_sizes[0] / 3;
    const int pt_blocks = (total_pts + BLK - 1) / BLK;

    const size_t need = SORTED_OFF + (size_t)total_pts * 16;
    const bool std_shape = (out_size == 32 * 128 * 128 * 128) &&
                           (total_pts == 32 * 65536) && (ws_size >= need);
    if (!std_shape) {
        zero_kernel<<<2048, BLK, 0, stream>>>((float4*)d_out, out_size / 4);
        naive_kernel<<<pt_blocks, BLK, 0, stream>>>(pts, scale_p, out, total_pts, out_size);
        return;
    }

    int* hist    = (int*)(ws + HIST_OFF);
    int* prefix  = (int*)(ws + PREFIX_OFF);
    int* cursor  = (int*)(ws + CURSOR_OFF);
    int* partial = (int*)(ws + PART_OFF);
    int* partExc = (int*)(ws + PARTEXC_OFF);
    float4* sorted = (float4*)(ws + SORTED_OFF);

    hipMemsetAsync(hist, 0, (size_t)NBINS * 4, stream);
    hist_kernel<<<pt_blocks, BLK, 0, stream>>>(pts, scale_p, hist, total_pts, out_size);
    scan_partial<<<NCHUNK, BLK, 0, stream>>>(hist, partial);
    scan_top<<<1, NCHUNK, 0, stream>>>(partial, partExc);
    scan_chunks<<<NCHUNK, SCAN_CHUNK, 0, stream>>>(hist, partExc, prefix, cursor);
    scatter_kernel<<<pt_blocks, BLK, 0, stream>>>(pts, scale_p, cursor, sorted, total_pts, out_size);
    // after scatter, cursor[bin] == prefix[bin] + hist[bin] == end of bin
    gather_kernel<<<NBINS, 256, 0, stream>>>(sorted, prefix, cursor, scale_p, out, out_size);
}